// Round 14
// baseline (46.291 us; speedup 1.0000x reference)
//
#include <hip/hip_runtime.h>
#include <cstdint>
#include <cstddef>

#define Bn 16
#define Hn 512
#define Wn 1024
#define NTOP 2048
#define KMAX 512
#define PAIRCAP 2048
#define FBINS 4096
#define FBASE 126566      // (0x3DCCCCCD>>13); scores in (0.1,1) -> bins [0,3481]
#define KEYSN 4096
#define XS 9              // x strips: 122 output cols each (128-col float2 window)
#define XW 122
#define YS 16             // y strips: 32 rows per block (8 rows per wave)
#define SLOTS_B 128       // per-block slots (region 32x122, mean ~80 cand)
#define BLKS (XS * YS)    // 144 blocks per batch
#define NSLOT (BLKS * SLOTS_B)   // 18432 entries/batch (9 ulonglong2 per topk thread)

// ---------------- Kernel 1: barrier-free float2 register-column detect --------------
// R12 PMC chain: latency-bound, occupancy-limited. R13 = 4 waves/SIMD (VGPR>64 caps
// at 4). This round: 8-row strips, im[14] (28 data VGPRs), __launch_bounds__(256,8)
// forces <=64 VGPR -> 8 waves/SIMD cap, grid demand 9/SIMD -> ~2x TLP vs R13.
__global__ __launch_bounds__(256, 8) void detect_kernel(const float* __restrict__ gray,
                                                        const float* __restrict__ mask,
                                                        uint64_t* __restrict__ slots) {
    __shared__ uint64_t s_list[SLOTS_B];
    __shared__ int s_n;

    const int s    = blockIdx.x;
    const int yB   = blockIdx.y;
    const int b    = blockIdx.z;
    const int t    = threadIdx.x;
    const int lane = t & 63;
    const int w    = t >> 6;
    const int xb   = s * XW - 4;                 // even
    const int c0   = xb + 2 * lane;
    const int ybase = yB * 32 + w * 8;

    if (t == 0) s_n = 0;
    __syncthreads();

    const float* gb = gray + (size_t)b * Hn * Wn;
    const float* mb = mask + (size_t)b * Hn * Wn;
    const bool ok0 = (c0 >= 0) && (c0 < Wn);
    const bool ok1 = (c0 + 1 >= 0) && (c0 + 1 < Wn);
    const int cl = c0 < 0 ? 0 : (c0 > Wn - 2 ? Wn - 2 : c0);
    const float NINF = -__builtin_inff();

    float2 im[14];
#pragma unroll
    for (int rr = 0; rr < 14; ++rr) {
        int gy = ybase - 3 + rr;                 // wave-uniform
        int gyc = gy < 0 ? 0 : (gy >= Hn ? Hn - 1 : gy);
        const float2 g = *(const float2*)(gb + (size_t)gyc * Wn + cl);
        const float2 m = *(const float2*)(mb + (size_t)gyc * Wn + cl);
        bool rok = (gy >= 0) && (gy < Hn);
        im[rr].x = (rok && ok0) ? g.x * m.x : NINF;
        im[rr].y = (rok && ok1) ? g.y * m.y : NINF;
    }

#pragma unroll
    for (int r = 0; r < 8; ++r) {
        // vertical 7-max per element
        float ex = fmaxf(fmaxf(fmaxf(im[r].x, im[r+1].x), fmaxf(im[r+2].x, im[r+3].x)),
                         fmaxf(fmaxf(im[r+4].x, im[r+5].x), im[r+6].x));
        float ey = fmaxf(fmaxf(fmaxf(im[r].y, im[r+1].y), fmaxf(im[r+2].y, im[r+3].y)),
                         fmaxf(fmaxf(im[r+4].y, im[r+5].y), im[r+6].y));
        float p  = fmaxf(ex, ey);                // pair max (elems 2l, 2l+1)
        // horizontal 7-windows: elem 2l   = {e1[l-2], p[l-1], p[l], p[l+1]}
        //                       elem 2l+1 = {p[l-1], p[l], p[l+1], e0[l+2]}
        float eyu2 = __shfl_up(ey, 2, 64);
        float pu1  = __shfl_up(p, 1, 64);
        float pd1  = __shfl_down(p, 1, 64);
        float exd2 = __shfl_down(ex, 2, 64);
        float win0 = fmaxf(fmaxf(eyu2, pu1), fmaxf(p, pd1));
        float win1 = fmaxf(fmaxf(pu1, p), fmaxf(pd1, exd2));
        float v0 = im[r + 3].x, v1 = im[r + 3].y;
        if (lane >= 2 && lane <= 62 && ok0 && v0 == win0 && v0 > 0.1f) {
            uint32_t idx = (uint32_t)((ybase + r) * Wn + c0);
            uint64_t key = ((uint64_t)__float_as_uint(v0) << 32) | (uint32_t)(~idx);
            int pos = atomicAdd(&s_n, 1);
            if (pos < SLOTS_B) s_list[pos] = key;
        }
        if (lane >= 1 && lane <= 61 && ok1 && v1 == win1 && v1 > 0.1f) {
            uint32_t idx = (uint32_t)((ybase + r) * Wn + c0 + 1);
            uint64_t key = ((uint64_t)__float_as_uint(v1) << 32) | (uint32_t)(~idx);
            int pos = atomicAdd(&s_n, 1);
            if (pos < SLOTS_B) s_list[pos] = key;
        }
    }
    __syncthreads();

    int m = s_n; if (m > SLOTS_B) m = SLOTS_B;
    const int blk = yB * XS + s;
    uint64_t* dst = slots + ((size_t)b * BLKS + blk) * SLOTS_B;
    if (t < SLOTS_B) dst[t] = (t < m) ? s_list[t] : 0ull;   // zero sentinel
}

// ---------------- Kernel 2: fused top-k + NMS, one block per batch ------------------
// (byte-identical to rounds 11/13: single register-resident global pass)
__global__ __launch_bounds__(1024) void topk_nms_kernel(const uint64_t* __restrict__ slots,
                                                        float* __restrict__ kp_out,
                                                        float* __restrict__ sc_out) {
    __shared__ uint64_t keys[KEYSN];
    __shared__ uint64_t keys2[NTOP];
    __shared__ int      hist[FBINS];
    __shared__ int      sfx[FBINS];
    __shared__ int      scanA[64];
    __shared__ uint32_t pairs[PAIRCAP];
    __shared__ uint8_t  keep[NTOP];
    __shared__ int      sel[KMAX];
    __shared__ int      misc[4];

    const int b = blockIdx.x;
    const int t = threadIdx.x;
    const int lane = t & 63;
    const int w = t >> 6;
    const ulonglong2* sb2 = (const ulonglong2*)(slots + (size_t)b * NSLOT);

    ulonglong2 ck[9];
#pragma unroll
    for (int k = 0; k < 9; ++k) ck[k] = sb2[t + (k << 10)];

    *(int4*)&hist[t << 2] = make_int4(0, 0, 0, 0);
    for (int i = t; i < NTOP; i += 1024) keys2[i] = 0ull;
    if (t < 4) misc[t] = 0;
    if (t < KMAX) sel[t] = -1;
    __syncthreads();

    // Phase A: histogram from registers
#pragma unroll
    for (int k = 0; k < 9; ++k) {
#pragma unroll
        for (int h = 0; h < 2; ++h) {
            uint32_t sbits = (uint32_t)((h ? ck[k].y : ck[k].x) >> 32);
            if (sbits) {
                int bin = (int)(sbits >> 13) - FBASE;
                bin = bin < 0 ? 0 : (bin > FBINS - 1 ? FBINS - 1 : bin);
                atomicAdd(&hist[bin], 1);
            }
        }
    }
    __syncthreads();

    // Phase B: hierarchical suffix scan over 4096 bins (thread t owns bins 4t..4t+3)
    const int base4 = t << 2;
    const int4 h4 = *(const int4*)&hist[base4];
    int loc = h4.x + h4.y + h4.z + h4.w;
    int x = loc;
#pragma unroll
    for (int d = 1; d < 64; d <<= 1) {
        int y = __shfl_down(x, d, 64);
        if (lane + d < 64) x += y;
    }
    if (lane == 0) scanA[w] = x;
    __syncthreads();
    if (w == 0) {
        int v = (lane < 16) ? scanA[lane] : 0;
#pragma unroll
        for (int d = 1; d < 16; d <<= 1) {
            int y = __shfl_down(v, d, 64);
            if (lane + d < 64) v += y;
        }
        if (lane < 16) scanA[lane] = v;
    }
    __syncthreads();
    const int total = scanA[0];
    const int target = total < NTOP ? total : NTOP;
    const int S_incl = x + ((w < 15) ? scanA[w + 1] : 0);

    int r = S_incl - loc;
    int s3 = r + h4.w;
    int s2 = s3 + h4.z;
    int s1 = s2 + h4.y;
    int s0 = s1 + h4.x;
    *(int4*)&sfx[base4]  = make_int4(s0, s1, s2, s3);
    *(int4*)&hist[base4] = make_int4(s1, s2, s3, r);    // scatter cursors
    if (s0 >= target && s1 < target) misc[2] = base4;
    if (s1 >= target && s2 < target) misc[2] = base4 + 1;
    if (s2 >= target && s3 < target) misc[2] = base4 + 2;
    if (s3 >= target && (base4 + 3 == FBINS - 1 || r < target)) misc[2] = base4 + 3;
    __syncthreads();
    const int T = misc[2];
    int cnt = sfx[T]; if (cnt > KEYSN) cnt = KEYSN;

    // Phase C: scatter replayed from registers (no second global pass)
#pragma unroll
    for (int k = 0; k < 9; ++k) {
#pragma unroll
        for (int h = 0; h < 2; ++h) {
            uint64_t key = h ? ck[k].y : ck[k].x;
            uint32_t sbits = (uint32_t)(key >> 32);
            if (sbits) {
                int bin = (int)(sbits >> 13) - FBASE;
                bin = bin < 0 ? 0 : (bin > FBINS - 1 ? FBINS - 1 : bin);
                if (bin >= T) {
                    int pos = atomicAdd(&hist[bin], 1);
                    if (pos < KEYSN) keys[pos] = key;
                }
            }
        }
    }
    __syncthreads();

    // Phase D: parallel rank-scatter sort (keys distinct => exact total order)
    for (int e = t; e < cnt; e += 1024) {
        uint64_t key = keys[e];
        uint32_t sbits = (uint32_t)(key >> 32);
        int bin = (int)(sbits >> 13) - FBASE;
        bin = bin < 0 ? 0 : (bin > FBINS - 1 ? FBINS - 1 : bin);
        int a0 = (bin + 1 < FBINS) ? sfx[bin + 1] : 0;
        int e0 = sfx[bin]; if (e0 > KEYSN) e0 = KEYSN;
        int rank = a0;
        for (int q = a0; q < e0; ++q) rank += (keys[q] > key) ? 1 : 0;
        if (rank < NTOP) keys2[rank] = key;
    }
    __syncthreads();

    // Phase E: keep init + conflict pairs within equal-score runs only (two valid
    // candidates with dist<3 lie in each other's 7x7 window => equal pooled max)
    for (int j = t; j < NTOP; j += 1024) {
        uint32_t sc = (uint32_t)(keys2[j] >> 32);
        keep[j] = (sc != 0u) ? 1 : 0;
        if (sc) {
            uint32_t idx = ~(uint32_t)keys2[j];
            int xq = (int)(idx & (Wn - 1)), yq = (int)(idx >> 10);
            for (int i = j - 1; i >= 0 && (uint32_t)(keys2[i] >> 32) == sc; --i) {
                uint32_t idx2 = ~(uint32_t)keys2[i];
                int dx = xq - (int)(idx2 & (Wn - 1));
                int dy = yq - (int)(idx2 >> 10);
                if (dx * dx + dy * dy < 9) {        // dist < R=3, exact in integers
                    int p = atomicAdd(&misc[1], 1);
                    if (p < PAIRCAP) pairs[p] = ((uint32_t)j << 16) | (uint32_t)i;
                }
            }
        }
    }
    __syncthreads();

    if (t == 0) {   // sequential greedy resolve (tiny; canonical order via sort)
        int pc = misc[1]; if (pc > PAIRCAP) pc = PAIRCAP;
        for (int a = 1; a < pc; ++a) {
            uint32_t v = pairs[a]; int q = a - 1;
            while (q >= 0 && pairs[q] > v) { pairs[q + 1] = pairs[q]; --q; }
            pairs[q + 1] = v;
        }
        for (int a = 0; a < pc; ++a) {
            int j = (int)(pairs[a] >> 16), i = (int)(pairs[a] & 0xFFFF);
            if (keep[i]) keep[j] = 0;
        }
    }
    __syncthreads();

    // Phase F: compaction prefix scan, select first 512 kept
    int j0 = 2 * t, j1 = j0 + 1;
    int k0 = keep[j0], k1 = keep[j1];
    int sum = k0 + k1;
    int xp = sum;
#pragma unroll
    for (int d = 1; d < 64; d <<= 1) {
        int y = __shfl_up(xp, d, 64);
        if (lane >= d) xp += y;
    }
    if (lane == 63) scanA[w] = xp;
    __syncthreads();
    if (w == 0) {
        int v = (lane < 16) ? scanA[lane] : 0;
#pragma unroll
        for (int d = 1; d < 16; d <<= 1) {
            int y = __shfl_up(v, d, 64);
            if (lane >= d) v += y;
        }
        if (lane < 16) scanA[lane] = v;
    }
    __syncthreads();
    int pre = xp + ((w > 0) ? scanA[w - 1] : 0);
    int ex = pre - sum;
    if (k0 && ex < KMAX) sel[ex] = j0;
    if (k1 && (ex + k0) < KMAX) sel[ex + k0] = j1;
    __syncthreads();

    if (t < KMAX) {
        int jj = sel[t];
        float xo = 0.f, yo = 0.f, so = 0.f;
        if (jj >= 0) {
            uint32_t idx = ~(uint32_t)keys2[jj];
            xo = (float)(idx & (Wn - 1));
            yo = (float)(idx >> 10);
            so = __uint_as_float((uint32_t)(keys2[jj] >> 32));
        }
        kp_out[(size_t)b * KMAX * 2 + 2 * t]     = xo;
        kp_out[(size_t)b * KMAX * 2 + 2 * t + 1] = yo;
        sc_out[(size_t)b * KMAX + t]             = so;
    }
}

extern "C" void kernel_launch(void* const* d_in, const int* in_sizes, int n_in,
                              void* d_out, int out_size, void* d_ws, size_t ws_size,
                              hipStream_t stream) {
    const float* gray = (const float*)d_in[0];
    const float* mask = (const float*)d_in[1];
    float* out = (float*)d_out;
    float* kp_out = out;                        // 16*512*2
    float* sc_out = out + (size_t)Bn * KMAX * 2;

    uint64_t* slots = (uint64_t*)d_ws;          // 16*144*128*8 = 2.36 MB, fully rewritten

    dim3 g1(XS, YS, Bn);                        // (9, 16, 16) = 2304 blocks
    detect_kernel<<<g1, 256, 0, stream>>>(gray, mask, slots);
    topk_nms_kernel<<<Bn, 1024, 0, stream>>>(slots, kp_out, sc_out);
}

// Round 15
// 41.186 us; speedup vs baseline: 1.1240x; 1.1240x over previous
//
#include <hip/hip_runtime.h>
#include <cstdint>
#include <cstddef>

#define Bn 16
#define Hn 512
#define Wn 1024
#define NTOP 2048
#define KMAX 512
#define PAIRCAP 2048
#define FBINS 4096
#define FBASE 126566      // (0x3DCCCCCD>>13); scores in (0.1,1) -> bins [0,3481]
#define KEYSN 4096
#define XS 9              // x strips: 122 output cols each (128-col float2 window)
#define XW 122
#define YS 16             // y strips: 32 rows per block (8 rows per wave)
#define SLOTS_B 128       // per-block slots (region 32x122, mean ~80 cand)
#define BLKS (XS * YS)    // 144 blocks per batch
#define NSLOT (BLKS * SLOTS_B)   // 18432 entries/batch (9 ulonglong2 per topk thread)

// ---------------- Kernel 1: software-pipelined rolling-window detect ----------------
// R12-R14 chain: latency-bound, occupancy-limited; 8 waves/SIMD needs <=64 VGPR, but
// R14's issue-all-14-loads pattern couldn't fit -> spill/serialize -> regression.
// This version: 11 NAMED float2 regs (22 data VGPRs). Preload window rows 0..10 (one
// latency exposure), then each output row consumes a 7-reg window and reuses the
// retiring register for the row-11..13 tail loads (issued 4-7 rows before use).
// All static names, no arrays, no movs. Target ~50 VGPR -> true 8 waves/SIMD.
__global__ __launch_bounds__(256, 8) void detect_kernel(const float* __restrict__ gray,
                                                        const float* __restrict__ mask,
                                                        uint64_t* __restrict__ slots) {
    __shared__ uint64_t s_list[SLOTS_B];
    __shared__ int s_n;

    const int s    = blockIdx.x;
    const int yB   = blockIdx.y;
    const int b    = blockIdx.z;
    const int t    = threadIdx.x;
    const int lane = t & 63;
    const int w    = t >> 6;
    const int xb   = s * XW - 4;                 // even
    const int c0   = xb + 2 * lane;
    const int ybase = yB * 32 + w * 8;

    if (t == 0) s_n = 0;
    __syncthreads();

    const float* gb = gray + (size_t)b * Hn * Wn;
    const float* mb = mask + (size_t)b * Hn * Wn;
    const bool ok0 = (c0 >= 0) && (c0 < Wn);
    const bool ok1 = (c0 + 1 >= 0) && (c0 + 1 < Wn);
    const int cl = c0 < 0 ? 0 : (c0 > Wn - 2 ? Wn - 2 : c0);
    const float NINF = -__builtin_inff();

    auto ld = [&](int rr) -> float2 {            // row rr of the 14-row window
        int gy = ybase - 3 + rr;                 // wave-uniform
        int gyc = gy < 0 ? 0 : (gy >= Hn ? Hn - 1 : gy);
        const float2 g = *(const float2*)(gb + (size_t)gyc * Wn + cl);
        const float2 m = *(const float2*)(mb + (size_t)gyc * Wn + cl);
        bool rok = (gy >= 0) && (gy < Hn);
        float2 r;
        r.x = (rok && ok0) ? g.x * m.x : NINF;
        r.y = (rok && ok1) ? g.y * m.y : NINF;
        return r;
    };

    float2 R0 = ld(0), R1 = ld(1), R2 = ld(2), R3 = ld(3), R4 = ld(4), R5 = ld(5),
           R6 = ld(6), R7 = ld(7), R8 = ld(8), R9 = ld(9), R10 = ld(10);

    // One output row: window regs A..G = rows r..r+6, center D = row ybase+r.
#define OUTROW(ROW, A,B,C,D,E,F,G) do {                                              \
        float ex = fmaxf(fmaxf(fmaxf(A.x, B.x), fmaxf(C.x, D.x)),                    \
                         fmaxf(fmaxf(E.x, F.x), G.x));                               \
        float ey = fmaxf(fmaxf(fmaxf(A.y, B.y), fmaxf(C.y, D.y)),                    \
                         fmaxf(fmaxf(E.y, F.y), G.y));                               \
        float p  = fmaxf(ex, ey);                                                    \
        float eyu2 = __shfl_up(ey, 2, 64);                                           \
        float pu1  = __shfl_up(p, 1, 64);                                            \
        float pd1  = __shfl_down(p, 1, 64);                                          \
        float exd2 = __shfl_down(ex, 2, 64);                                         \
        float win0 = fmaxf(fmaxf(eyu2, pu1), fmaxf(p, pd1));                         \
        float win1 = fmaxf(fmaxf(pu1, p), fmaxf(pd1, exd2));                         \
        float v0 = D.x, v1 = D.y;                                                    \
        if (lane >= 2 && lane <= 62 && ok0 && v0 == win0 && v0 > 0.1f) {             \
            uint32_t idx = (uint32_t)((ybase + (ROW)) * Wn + c0);                    \
            uint64_t key = ((uint64_t)__float_as_uint(v0) << 32) | (uint32_t)(~idx); \
            int pos = atomicAdd(&s_n, 1);                                            \
            if (pos < SLOTS_B) s_list[pos] = key;                                    \
        }                                                                            \
        if (lane >= 1 && lane <= 61 && ok1 && v1 == win1 && v1 > 0.1f) {             \
            uint32_t idx = (uint32_t)((ybase + (ROW)) * Wn + c0 + 1);                \
            uint64_t key = ((uint64_t)__float_as_uint(v1) << 32) | (uint32_t)(~idx); \
            int pos = atomicAdd(&s_n, 1);                                            \
            if (pos < SLOTS_B) s_list[pos] = key;                                    \
        }                                                                            \
    } while (0)

    OUTROW(0, R0, R1, R2, R3, R4, R5, R6);   R0 = ld(11);
    OUTROW(1, R1, R2, R3, R4, R5, R6, R7);   R1 = ld(12);
    OUTROW(2, R2, R3, R4, R5, R6, R7, R8);   R2 = ld(13);
    OUTROW(3, R3, R4, R5, R6, R7, R8, R9);
    OUTROW(4, R4, R5, R6, R7, R8, R9, R10);
    OUTROW(5, R5, R6, R7, R8, R9, R10, R0);
    OUTROW(6, R6, R7, R8, R9, R10, R0, R1);
    OUTROW(7, R7, R8, R9, R10, R0, R1, R2);
#undef OUTROW
    __syncthreads();

    int m = s_n; if (m > SLOTS_B) m = SLOTS_B;
    const int blk = yB * XS + s;
    uint64_t* dst = slots + ((size_t)b * BLKS + blk) * SLOTS_B;
    if (t < SLOTS_B) dst[t] = (t < m) ? s_list[t] : 0ull;   // zero sentinel
}

// ---------------- Kernel 2: fused top-k + NMS, one block per batch ------------------
// (byte-identical to rounds 11/13: single register-resident global pass)
__global__ __launch_bounds__(1024) void topk_nms_kernel(const uint64_t* __restrict__ slots,
                                                        float* __restrict__ kp_out,
                                                        float* __restrict__ sc_out) {
    __shared__ uint64_t keys[KEYSN];
    __shared__ uint64_t keys2[NTOP];
    __shared__ int      hist[FBINS];
    __shared__ int      sfx[FBINS];
    __shared__ int      scanA[64];
    __shared__ uint32_t pairs[PAIRCAP];
    __shared__ uint8_t  keep[NTOP];
    __shared__ int      sel[KMAX];
    __shared__ int      misc[4];

    const int b = blockIdx.x;
    const int t = threadIdx.x;
    const int lane = t & 63;
    const int w = t >> 6;
    const ulonglong2* sb2 = (const ulonglong2*)(slots + (size_t)b * NSLOT);

    ulonglong2 ck[9];
#pragma unroll
    for (int k = 0; k < 9; ++k) ck[k] = sb2[t + (k << 10)];

    *(int4*)&hist[t << 2] = make_int4(0, 0, 0, 0);
    for (int i = t; i < NTOP; i += 1024) keys2[i] = 0ull;
    if (t < 4) misc[t] = 0;
    if (t < KMAX) sel[t] = -1;
    __syncthreads();

    // Phase A: histogram from registers
#pragma unroll
    for (int k = 0; k < 9; ++k) {
#pragma unroll
        for (int h = 0; h < 2; ++h) {
            uint32_t sbits = (uint32_t)((h ? ck[k].y : ck[k].x) >> 32);
            if (sbits) {
                int bin = (int)(sbits >> 13) - FBASE;
                bin = bin < 0 ? 0 : (bin > FBINS - 1 ? FBINS - 1 : bin);
                atomicAdd(&hist[bin], 1);
            }
        }
    }
    __syncthreads();

    // Phase B: hierarchical suffix scan over 4096 bins (thread t owns bins 4t..4t+3)
    const int base4 = t << 2;
    const int4 h4 = *(const int4*)&hist[base4];
    int loc = h4.x + h4.y + h4.z + h4.w;
    int x = loc;
#pragma unroll
    for (int d = 1; d < 64; d <<= 1) {
        int y = __shfl_down(x, d, 64);
        if (lane + d < 64) x += y;
    }
    if (lane == 0) scanA[w] = x;
    __syncthreads();
    if (w == 0) {
        int v = (lane < 16) ? scanA[lane] : 0;
#pragma unroll
        for (int d = 1; d < 16; d <<= 1) {
            int y = __shfl_down(v, d, 64);
            if (lane + d < 64) v += y;
        }
        if (lane < 16) scanA[lane] = v;
    }
    __syncthreads();
    const int total = scanA[0];
    const int target = total < NTOP ? total : NTOP;
    const int S_incl = x + ((w < 15) ? scanA[w + 1] : 0);

    int r = S_incl - loc;
    int s3 = r + h4.w;
    int s2 = s3 + h4.z;
    int s1 = s2 + h4.y;
    int s0 = s1 + h4.x;
    *(int4*)&sfx[base4]  = make_int4(s0, s1, s2, s3);
    *(int4*)&hist[base4] = make_int4(s1, s2, s3, r);    // scatter cursors
    if (s0 >= target && s1 < target) misc[2] = base4;
    if (s1 >= target && s2 < target) misc[2] = base4 + 1;
    if (s2 >= target && s3 < target) misc[2] = base4 + 2;
    if (s3 >= target && (base4 + 3 == FBINS - 1 || r < target)) misc[2] = base4 + 3;
    __syncthreads();
    const int T = misc[2];
    int cnt = sfx[T]; if (cnt > KEYSN) cnt = KEYSN;

    // Phase C: scatter replayed from registers (no second global pass)
#pragma unroll
    for (int k = 0; k < 9; ++k) {
#pragma unroll
        for (int h = 0; h < 2; ++h) {
            uint64_t key = h ? ck[k].y : ck[k].x;
            uint32_t sbits = (uint32_t)(key >> 32);
            if (sbits) {
                int bin = (int)(sbits >> 13) - FBASE;
                bin = bin < 0 ? 0 : (bin > FBINS - 1 ? FBINS - 1 : bin);
                if (bin >= T) {
                    int pos = atomicAdd(&hist[bin], 1);
                    if (pos < KEYSN) keys[pos] = key;
                }
            }
        }
    }
    __syncthreads();

    // Phase D: parallel rank-scatter sort (keys distinct => exact total order)
    for (int e = t; e < cnt; e += 1024) {
        uint64_t key = keys[e];
        uint32_t sbits = (uint32_t)(key >> 32);
        int bin = (int)(sbits >> 13) - FBASE;
        bin = bin < 0 ? 0 : (bin > FBINS - 1 ? FBINS - 1 : bin);
        int a0 = (bin + 1 < FBINS) ? sfx[bin + 1] : 0;
        int e0 = sfx[bin]; if (e0 > KEYSN) e0 = KEYSN;
        int rank = a0;
        for (int q = a0; q < e0; ++q) rank += (keys[q] > key) ? 1 : 0;
        if (rank < NTOP) keys2[rank] = key;
    }
    __syncthreads();

    // Phase E: keep init + conflict pairs within equal-score runs only (two valid
    // candidates with dist<3 lie in each other's 7x7 window => equal pooled max)
    for (int j = t; j < NTOP; j += 1024) {
        uint32_t sc = (uint32_t)(keys2[j] >> 32);
        keep[j] = (sc != 0u) ? 1 : 0;
        if (sc) {
            uint32_t idx = ~(uint32_t)keys2[j];
            int xq = (int)(idx & (Wn - 1)), yq = (int)(idx >> 10);
            for (int i = j - 1; i >= 0 && (uint32_t)(keys2[i] >> 32) == sc; --i) {
                uint32_t idx2 = ~(uint32_t)keys2[i];
                int dx = xq - (int)(idx2 & (Wn - 1));
                int dy = yq - (int)(idx2 >> 10);
                if (dx * dx + dy * dy < 9) {        // dist < R=3, exact in integers
                    int p = atomicAdd(&misc[1], 1);
                    if (p < PAIRCAP) pairs[p] = ((uint32_t)j << 16) | (uint32_t)i;
                }
            }
        }
    }
    __syncthreads();

    if (t == 0) {   // sequential greedy resolve (tiny; canonical order via sort)
        int pc = misc[1]; if (pc > PAIRCAP) pc = PAIRCAP;
        for (int a = 1; a < pc; ++a) {
            uint32_t v = pairs[a]; int q = a - 1;
            while (q >= 0 && pairs[q] > v) { pairs[q + 1] = pairs[q]; --q; }
            pairs[q + 1] = v;
        }
        for (int a = 0; a < pc; ++a) {
            int j = (int)(pairs[a] >> 16), i = (int)(pairs[a] & 0xFFFF);
            if (keep[i]) keep[j] = 0;
        }
    }
    __syncthreads();

    // Phase F: compaction prefix scan, select first 512 kept
    int j0 = 2 * t, j1 = j0 + 1;
    int k0 = keep[j0], k1 = keep[j1];
    int sum = k0 + k1;
    int xp = sum;
#pragma unroll
    for (int d = 1; d < 64; d <<= 1) {
        int y = __shfl_up(xp, d, 64);
        if (lane >= d) xp += y;
    }
    if (lane == 63) scanA[w] = xp;
    __syncthreads();
    if (w == 0) {
        int v = (lane < 16) ? scanA[lane] : 0;
#pragma unroll
        for (int d = 1; d < 16; d <<= 1) {
            int y = __shfl_up(v, d, 64);
            if (lane >= d) v += y;
        }
        if (lane < 16) scanA[lane] = v;
    }
    __syncthreads();
    int pre = xp + ((w > 0) ? scanA[w - 1] : 0);
    int ex = pre - sum;
    if (k0 && ex < KMAX) sel[ex] = j0;
    if (k1 && (ex + k0) < KMAX) sel[ex + k0] = j1;
    __syncthreads();

    if (t < KMAX) {
        int jj = sel[t];
        float xo = 0.f, yo = 0.f, so = 0.f;
        if (jj >= 0) {
            uint32_t idx = ~(uint32_t)keys2[jj];
            xo = (float)(idx & (Wn - 1));
            yo = (float)(idx >> 10);
            so = __uint_as_float((uint32_t)(keys2[jj] >> 32));
        }
        kp_out[(size_t)b * KMAX * 2 + 2 * t]     = xo;
        kp_out[(size_t)b * KMAX * 2 + 2 * t + 1] = yo;
        sc_out[(size_t)b * KMAX + t]             = so;
    }
}

extern "C" void kernel_launch(void* const* d_in, const int* in_sizes, int n_in,
                              void* d_out, int out_size, void* d_ws, size_t ws_size,
                              hipStream_t stream) {
    const float* gray = (const float*)d_in[0];
    const float* mask = (const float*)d_in[1];
    float* out = (float*)d_out;
    float* kp_out = out;                        // 16*512*2
    float* sc_out = out + (size_t)Bn * KMAX * 2;

    uint64_t* slots = (uint64_t*)d_ws;          // 16*144*128*8 = 2.36 MB, fully rewritten

    dim3 g1(XS, YS, Bn);                        // (9, 16, 16) = 2304 blocks
    detect_kernel<<<g1, 256, 0, stream>>>(gray, mask, slots);
    topk_nms_kernel<<<Bn, 1024, 0, stream>>>(slots, kp_out, sc_out);
}

// Round 16
// 36.056 us; speedup vs baseline: 1.2839x; 1.1423x over previous
//
#include <hip/hip_runtime.h>
#include <cstdint>
#include <cstddef>

#define Bn 16
#define Hn 512
#define Wn 1024
#define NTOP 2048
#define KMAX 512
#define PAIRCAP 2048
#define FBINS 4096
#define FBASE 126566      // (0x3DCCCCCD>>13); scores in (0.1,1) -> bins [0,3481]
#define KEYSN 4096
#define XS 9              // x strips: 122 output cols each (128-col float2 window)
#define XW 122
#define YS 8              // y strips: 64 rows per block (16 rows per wave)
#define SLOTS_B 256       // per-block slots (region 64x122, mean ~160 cand)
#define BLKS (XS * YS)    // 72 blocks per batch
#define NSLOT (BLKS * SLOTS_B)   // 18432 entries/batch (9 ulonglong2 per topk thread)

// ---------------- Kernel 1: barrier-free float2 register-column detect --------------
// BYTE-IDENTICAL to round 13 (measured best: ~15.5us). 16 rows/wave, im[22], grid
// (9,8,16)=1152 blocks -> 4.5 waves/SIMD demand vs VGPR cap 4. R14/R15 proved the
// 8-row/64-VGPR path regresses (halo + per-wave overhead); this geometry is optimal.
__global__ __launch_bounds__(256) void detect_kernel(const float* __restrict__ gray,
                                                     const float* __restrict__ mask,
                                                     uint64_t* __restrict__ slots) {
    __shared__ uint64_t s_list[SLOTS_B];
    __shared__ int s_n;

    const int s    = blockIdx.x;
    const int yB   = blockIdx.y;
    const int b    = blockIdx.z;
    const int t    = threadIdx.x;
    const int lane = t & 63;
    const int w    = t >> 6;
    const int xb   = s * XW - 4;                 // even
    const int c0   = xb + 2 * lane;
    const int ybase = yB * 64 + w * 16;

    if (t == 0) s_n = 0;
    __syncthreads();

    const float* gb = gray + (size_t)b * Hn * Wn;
    const float* mb = mask + (size_t)b * Hn * Wn;
    const bool ok0 = (c0 >= 0) && (c0 < Wn);
    const bool ok1 = (c0 + 1 >= 0) && (c0 + 1 < Wn);
    const int cl = c0 < 0 ? 0 : (c0 > Wn - 2 ? Wn - 2 : c0);
    const float NINF = -__builtin_inff();

    float2 im[22];
#pragma unroll
    for (int rr = 0; rr < 22; ++rr) {
        int gy = ybase - 3 + rr;                 // wave-uniform
        int gyc = gy < 0 ? 0 : (gy >= Hn ? Hn - 1 : gy);
        const float2 g = *(const float2*)(gb + (size_t)gyc * Wn + cl);
        const float2 m = *(const float2*)(mb + (size_t)gyc * Wn + cl);
        bool rok = (gy >= 0) && (gy < Hn);
        im[rr].x = (rok && ok0) ? g.x * m.x : NINF;
        im[rr].y = (rok && ok1) ? g.y * m.y : NINF;
    }

#pragma unroll
    for (int r = 0; r < 16; ++r) {
        // vertical 7-max per element
        float ex = fmaxf(fmaxf(fmaxf(im[r].x, im[r+1].x), fmaxf(im[r+2].x, im[r+3].x)),
                         fmaxf(fmaxf(im[r+4].x, im[r+5].x), im[r+6].x));
        float ey = fmaxf(fmaxf(fmaxf(im[r].y, im[r+1].y), fmaxf(im[r+2].y, im[r+3].y)),
                         fmaxf(fmaxf(im[r+4].y, im[r+5].y), im[r+6].y));
        float p  = fmaxf(ex, ey);                // pair max (elems 2l, 2l+1)
        // horizontal 7-windows: elem 2l   = {e1[l-2], p[l-1], p[l], p[l+1]}
        //                       elem 2l+1 = {p[l-1], p[l], p[l+1], e0[l+2]}
        float eyu2 = __shfl_up(ey, 2, 64);
        float pu1  = __shfl_up(p, 1, 64);
        float pd1  = __shfl_down(p, 1, 64);
        float exd2 = __shfl_down(ex, 2, 64);
        float win0 = fmaxf(fmaxf(eyu2, pu1), fmaxf(p, pd1));
        float win1 = fmaxf(fmaxf(pu1, p), fmaxf(pd1, exd2));
        float v0 = im[r + 3].x, v1 = im[r + 3].y;
        if (lane >= 2 && lane <= 62 && ok0 && v0 == win0 && v0 > 0.1f) {
            uint32_t idx = (uint32_t)((ybase + r) * Wn + c0);
            uint64_t key = ((uint64_t)__float_as_uint(v0) << 32) | (uint32_t)(~idx);
            int pos = atomicAdd(&s_n, 1);
            if (pos < SLOTS_B) s_list[pos] = key;
        }
        if (lane >= 1 && lane <= 61 && ok1 && v1 == win1 && v1 > 0.1f) {
            uint32_t idx = (uint32_t)((ybase + r) * Wn + c0 + 1);
            uint64_t key = ((uint64_t)__float_as_uint(v1) << 32) | (uint32_t)(~idx);
            int pos = atomicAdd(&s_n, 1);
            if (pos < SLOTS_B) s_list[pos] = key;
        }
    }
    __syncthreads();

    int m = s_n; if (m > SLOTS_B) m = SLOTS_B;
    const int blk = yB * XS + s;
    uint64_t* dst = slots + ((size_t)b * BLKS + blk) * SLOTS_B;
    dst[t] = (t < m) ? s_list[t] : 0ull;        // SLOTS_B == blockDim: one store each
}

// ---------------- Kernel 2: fused top-k + NMS, one block per batch ------------------
// Slimmed vs R13: (1) sfx[] LDS removed — after the scatter, hist[j] == sfx[j] for all
// bins >= T (cursor start sfx[j+1] + count = sfx[j]), so Phase D reads bounds from
// post-scatter hist; crossing thread stashes cnt in misc[3]. (2) dead keys[] zero-fill
// removed (Phase D only touches slots < cnt, which the scatter fully populates).
__global__ __launch_bounds__(1024) void topk_nms_kernel(const uint64_t* __restrict__ slots,
                                                        float* __restrict__ kp_out,
                                                        float* __restrict__ sc_out) {
    __shared__ uint64_t keys[KEYSN];     // bin-grouped, unsorted within bin
    __shared__ uint64_t keys2[NTOP];     // globally sorted top-2048
    __shared__ int      hist[FBINS];     // counts -> cursors -> (post-scatter) sfx
    __shared__ int      scanA[64];
    __shared__ uint32_t pairs[PAIRCAP];
    __shared__ uint8_t  keep[NTOP];
    __shared__ int      sel[KMAX];
    __shared__ int      misc[4];         // 1: pair count, 2: T, 3: cnt

    const int b = blockIdx.x;
    const int t = threadIdx.x;
    const int lane = t & 63;
    const int w = t >> 6;
    const ulonglong2* sb2 = (const ulonglong2*)(slots + (size_t)b * NSLOT);

    ulonglong2 ck[9];
#pragma unroll
    for (int k = 0; k < 9; ++k) ck[k] = sb2[t + (k << 10)];

    *(int4*)&hist[t << 2] = make_int4(0, 0, 0, 0);
    for (int i = t; i < NTOP; i += 1024) keys2[i] = 0ull;
    if (t < 4) misc[t] = 0;
    if (t < KMAX) sel[t] = -1;
    __syncthreads();

    // Phase A: histogram from registers
#pragma unroll
    for (int k = 0; k < 9; ++k) {
#pragma unroll
        for (int h = 0; h < 2; ++h) {
            uint32_t sbits = (uint32_t)((h ? ck[k].y : ck[k].x) >> 32);
            if (sbits) {
                int bin = (int)(sbits >> 13) - FBASE;
                bin = bin < 0 ? 0 : (bin > FBINS - 1 ? FBINS - 1 : bin);
                atomicAdd(&hist[bin], 1);
            }
        }
    }
    __syncthreads();

    // Phase B: hierarchical suffix scan over 4096 bins (thread t owns bins 4t..4t+3)
    const int base4 = t << 2;
    const int4 h4 = *(const int4*)&hist[base4];
    int loc = h4.x + h4.y + h4.z + h4.w;
    int x = loc;
#pragma unroll
    for (int d = 1; d < 64; d <<= 1) {
        int y = __shfl_down(x, d, 64);
        if (lane + d < 64) x += y;
    }
    if (lane == 0) scanA[w] = x;
    __syncthreads();
    if (w == 0) {
        int v = (lane < 16) ? scanA[lane] : 0;
#pragma unroll
        for (int d = 1; d < 16; d <<= 1) {
            int y = __shfl_down(v, d, 64);
            if (lane + d < 64) v += y;
        }
        if (lane < 16) scanA[lane] = v;
    }
    __syncthreads();
    const int total = scanA[0];
    const int target = total < NTOP ? total : NTOP;
    const int S_incl = x + ((w < 15) ? scanA[w + 1] : 0);

    int r = S_incl - loc;                        // sfx[base4+4]
    int s3 = r + h4.w;
    int s2 = s3 + h4.z;
    int s1 = s2 + h4.y;
    int s0 = s1 + h4.x;
    *(int4*)&hist[base4] = make_int4(s1, s2, s3, r);    // scatter cursors (= bin starts)
    // unique crossing bin T: sfx[T] >= target > sfx[T+1]; owner also records cnt
    if (s0 >= target && s1 < target) { misc[2] = base4;     misc[3] = s0 < KEYSN ? s0 : KEYSN; }
    if (s1 >= target && s2 < target) { misc[2] = base4 + 1; misc[3] = s1 < KEYSN ? s1 : KEYSN; }
    if (s2 >= target && s3 < target) { misc[2] = base4 + 2; misc[3] = s2 < KEYSN ? s2 : KEYSN; }
    if (s3 >= target && (base4 + 3 == FBINS - 1 || r < target)) {
        misc[2] = base4 + 3; misc[3] = s3 < KEYSN ? s3 : KEYSN;
    }
    __syncthreads();
    const int T = misc[2];
    const int cnt = misc[3];

    // Phase C: scatter replayed from registers; afterwards hist[j] == sfx[j] for j >= T
#pragma unroll
    for (int k = 0; k < 9; ++k) {
#pragma unroll
        for (int h = 0; h < 2; ++h) {
            uint64_t key = h ? ck[k].y : ck[k].x;
            uint32_t sbits = (uint32_t)(key >> 32);
            if (sbits) {
                int bin = (int)(sbits >> 13) - FBASE;
                bin = bin < 0 ? 0 : (bin > FBINS - 1 ? FBINS - 1 : bin);
                if (bin >= T) {
                    int pos = atomicAdd(&hist[bin], 1);
                    if (pos < KEYSN) keys[pos] = key;
                }
            }
        }
    }
    __syncthreads();

    // Phase D: parallel rank-scatter sort (bounds from post-scatter hist)
    for (int e = t; e < cnt; e += 1024) {
        uint64_t key = keys[e];
        uint32_t sbits = (uint32_t)(key >> 32);
        int bin = (int)(sbits >> 13) - FBASE;
        bin = bin < 0 ? 0 : (bin > FBINS - 1 ? FBINS - 1 : bin);
        int a0 = (bin + 1 < FBINS) ? hist[bin + 1] : 0;
        int e0 = hist[bin]; if (e0 > KEYSN) e0 = KEYSN;
        int rank = a0;
        for (int q = a0; q < e0; ++q) rank += (keys[q] > key) ? 1 : 0;
        if (rank < NTOP) keys2[rank] = key;
    }
    __syncthreads();

    // Phase E: keep init + conflict pairs within equal-score runs only (two valid
    // candidates with dist<3 lie in each other's 7x7 window => equal pooled max)
    for (int j = t; j < NTOP; j += 1024) {
        uint32_t sc = (uint32_t)(keys2[j] >> 32);
        keep[j] = (sc != 0u) ? 1 : 0;
        if (sc) {
            uint32_t idx = ~(uint32_t)keys2[j];
            int xq = (int)(idx & (Wn - 1)), yq = (int)(idx >> 10);
            for (int i = j - 1; i >= 0 && (uint32_t)(keys2[i] >> 32) == sc; --i) {
                uint32_t idx2 = ~(uint32_t)keys2[i];
                int dx = xq - (int)(idx2 & (Wn - 1));
                int dy = yq - (int)(idx2 >> 10);
                if (dx * dx + dy * dy < 9) {        // dist < R=3, exact in integers
                    int p = atomicAdd(&misc[1], 1);
                    if (p < PAIRCAP) pairs[p] = ((uint32_t)j << 16) | (uint32_t)i;
                }
            }
        }
    }
    __syncthreads();

    if (t == 0) {   // sequential greedy resolve (tiny; canonical order via sort)
        int pc = misc[1]; if (pc > PAIRCAP) pc = PAIRCAP;
        for (int a = 1; a < pc; ++a) {
            uint32_t v = pairs[a]; int q = a - 1;
            while (q >= 0 && pairs[q] > v) { pairs[q + 1] = pairs[q]; --q; }
            pairs[q + 1] = v;
        }
        for (int a = 0; a < pc; ++a) {
            int j = (int)(pairs[a] >> 16), i = (int)(pairs[a] & 0xFFFF);
            if (keep[i]) keep[j] = 0;
        }
    }
    __syncthreads();

    // Phase F: compaction prefix scan, select first 512 kept
    int j0 = 2 * t, j1 = j0 + 1;
    int k0 = keep[j0], k1 = keep[j1];
    int sum = k0 + k1;
    int xp = sum;
#pragma unroll
    for (int d = 1; d < 64; d <<= 1) {
        int y = __shfl_up(xp, d, 64);
        if (lane >= d) xp += y;
    }
    if (lane == 63) scanA[w] = xp;
    __syncthreads();
    if (w == 0) {
        int v = (lane < 16) ? scanA[lane] : 0;
#pragma unroll
        for (int d = 1; d < 16; d <<= 1) {
            int y = __shfl_up(v, d, 64);
            if (lane >= d) v += y;
        }
        if (lane < 16) scanA[lane] = v;
    }
    __syncthreads();
    int pre = xp + ((w > 0) ? scanA[w - 1] : 0);
    int ex = pre - sum;
    if (k0 && ex < KMAX) sel[ex] = j0;
    if (k1 && (ex + k0) < KMAX) sel[ex + k0] = j1;
    __syncthreads();

    if (t < KMAX) {
        int jj = sel[t];
        float xo = 0.f, yo = 0.f, so = 0.f;
        if (jj >= 0) {
            uint32_t idx = ~(uint32_t)keys2[jj];
            xo = (float)(idx & (Wn - 1));
            yo = (float)(idx >> 10);
            so = __uint_as_float((uint32_t)(keys2[jj] >> 32));
        }
        kp_out[(size_t)b * KMAX * 2 + 2 * t]     = xo;
        kp_out[(size_t)b * KMAX * 2 + 2 * t + 1] = yo;
        sc_out[(size_t)b * KMAX + t]             = so;
    }
}

extern "C" void kernel_launch(void* const* d_in, const int* in_sizes, int n_in,
                              void* d_out, int out_size, void* d_ws, size_t ws_size,
                              hipStream_t stream) {
    const float* gray = (const float*)d_in[0];
    const float* mask = (const float*)d_in[1];
    float* out = (float*)d_out;
    float* kp_out = out;                        // 16*512*2
    float* sc_out = out + (size_t)Bn * KMAX * 2;

    uint64_t* slots = (uint64_t*)d_ws;          // 16*72*256*8 = 2.36 MB, fully rewritten

    dim3 g1(XS, YS, Bn);                        // (9, 8, 16) = 1152 blocks
    detect_kernel<<<g1, 256, 0, stream>>>(gray, mask, slots);
    topk_nms_kernel<<<Bn, 1024, 0, stream>>>(slots, kp_out, sc_out);
}